// Round 3
// baseline (3065.628 us; speedup 1.0000x reference)
//
#include <hip/hip_runtime.h>
#include <hip/hip_bf16.h>
#include <cfloat>

static constexpr int NBAT = 16;    // batch
static constexpr int NPT  = 2048;  // points

// ---------------------------------------------------------------------------
// mlp1 layer 0: h1[b][o][n] = relu(b0[o] + sum_{c<3} w0[o][c] * in[b][n][c])
// grid (NPT/256, 128, B), block 256.  ALL global data is fp32.
// ---------------------------------------------------------------------------
__global__ __launch_bounds__(256) void k_mlp1a(const float* __restrict__ in,
                                               const float* __restrict__ w0,
                                               const float* __restrict__ b0,
                                               float* __restrict__ h1)
{
  const int n = blockIdx.x * 256 + threadIdx.x;
  const int o = blockIdx.y;
  const int b = blockIdx.z;
  const float wa = w0[o*3+0], wb = w0[o*3+1], wc = w0[o*3+2];
  const float* ip = in + ((long)b*NPT + n)*3;
  float v = b0[o];
  v = fmaf(wa, ip[0], v);
  v = fmaf(wb, ip[1], v);
  v = fmaf(wc, ip[2], v);
  h1[((long)b*128 + o)*NPT + n] = fmaxf(v, 0.f);
}

// ---------------------------------------------------------------------------
// Generic 1x1-conv GEMM: OUT[b][ocol+o][n] = act(bias(o,b) + sum_k W[o][k]*X[b][k][n])
// W row-major fp32 with row stride wld. X fp32 [b][K][NPT] (batch stride xbs).
// MAXRED: reduce max over n per o into partial[(b*mtot+o)*gridDim.x + bx].
// block 256 = (BM/TM)x(BN/TN); grid (NPT/BN, M/BM, B)
// ---------------------------------------------------------------------------
template<int BM,int BN,int BK,int TM,int TN,bool RELU,bool BIAS,bool B2D,bool MAXRED>
__global__ __launch_bounds__(256) void conv_gemm(
    const float* __restrict__ W, int wld, int K,
    const float* __restrict__ bias,
    const float* __restrict__ bias2d, int mtot,
    const float* __restrict__ X, long xbs,
    float* __restrict__ OUT, long obs, int ocol,
    float* __restrict__ partial)
{
  static_assert((BM/TM)*(BN/TN) == 256, "bad mapping");
  __shared__ float Ws[BK][BM];
  __shared__ float Xs[BK][BN];
  __shared__ float red[MAXRED ? BM*17 : 1];
  const int b  = blockIdx.z;
  const int n0 = blockIdx.x * BN;
  const int o0 = blockIdx.y * BM;
  const int tid = threadIdx.x;
  const int tn = tid % (BN/TN);
  const int to = tid / (BN/TN);
  const float* Xb = X + (long)b * xbs;
  float acc[TM][TN];
  #pragma unroll
  for (int i=0;i<TM;++i)
    #pragma unroll
    for (int j=0;j<TN;++j) acc[i][j] = 0.f;

  for (int k0 = 0; k0 < K; k0 += BK) {
    for (int e = tid; e < BM*BK; e += 256) {
      int k = e % BK, o = e / BK;
      Ws[k][o] = W[(long)(o0+o)*wld + k0 + k];
    }
    for (int e = tid; e < BK*BN; e += 256) {
      int k = e / BN, n = e % BN;
      Xs[k][n] = Xb[(long)(k0+k)*NPT + n0 + n];
    }
    __syncthreads();
    #pragma unroll
    for (int k=0;k<BK;++k) {
      float a[TM], xv[TN];
      #pragma unroll
      for (int i=0;i<TM;++i) a[i] = Ws[k][to*TM+i];
      #pragma unroll
      for (int j=0;j<TN;++j) xv[j] = Xs[k][tn*TN+j];
      #pragma unroll
      for (int i=0;i<TM;++i)
        #pragma unroll
        for (int j=0;j<TN;++j) acc[i][j] = fmaf(a[i], xv[j], acc[i][j]);
    }
    __syncthreads();
  }

  if constexpr (!MAXRED) {
    #pragma unroll
    for (int i=0;i<TM;++i) {
      const int o = o0 + to*TM + i;
      float bi = 0.f;
      if constexpr (BIAS) bi = bias[o];
      if constexpr (B2D)  bi += bias2d[b*mtot + o];
      float* op = OUT + (long)b*obs + (long)(ocol + o)*NPT + n0 + tn*TN;
      #pragma unroll
      for (int j=0;j<TN;++j) {
        float vv = acc[i][j] + bi;
        if constexpr (RELU) vv = fmaxf(vv, 0.f);
        op[j] = vv;
      }
    }
  } else {
    #pragma unroll
    for (int i=0;i<TM;++i) {
      const int o = o0 + to*TM + i;
      float bi = BIAS ? bias[o] : 0.f;
      float mx = -FLT_MAX;
      #pragma unroll
      for (int j=0;j<TN;++j) mx = fmaxf(mx, acc[i][j] + bi);
      red[(to*TM+i)*17 + tn] = mx;
    }
    __syncthreads();
    for (int o = tid; o < BM; o += 256) {
      float mx = -FLT_MAX;
      #pragma unroll
      for (int t=0;t<BN/TN;++t) mx = fmaxf(mx, red[o*17+t]);
      partial[((long)b*mtot + o0 + o) * gridDim.x + blockIdx.x] = mx;
    }
  }
}

// ---------------------------------------------------------------------------
// global max over points: gmax[b*128+c] = max_n lf[b][c][n].  grid (B*128), 256
// ---------------------------------------------------------------------------
__global__ __launch_bounds__(256) void k_gmax(const float* __restrict__ lf,
                                              float* __restrict__ gmax)
{
  const int row = blockIdx.x;
  const float* p = lf + (long)row*NPT;
  float m = -FLT_MAX;
  for (int i = threadIdx.x; i < NPT; i += 256) m = fmaxf(m, p[i]);
  __shared__ float red[256];
  red[threadIdx.x] = m; __syncthreads();
  for (int s = 128; s > 0; s >>= 1) {
    if (threadIdx.x < s) red[threadIdx.x] = fmaxf(red[threadIdx.x], red[threadIdx.x+s]);
    __syncthreads();
  }
  if (threadIdx.x == 0) gmax[row] = red[0];
}

// ---------------------------------------------------------------------------
// gc[b][o] = b0[o] + sum_c w0[o][128+c] * gmax[b][c]   (w0 is [128][256] fp32)
// grid (B), block 128
// ---------------------------------------------------------------------------
__global__ __launch_bounds__(128) void k_gvec(const float* __restrict__ w0,
                                              const float* __restrict__ b0,
                                              const float* __restrict__ gmax,
                                              float* __restrict__ gc)
{
  const int b = blockIdx.x, o = threadIdx.x;
  __shared__ float g[128];
  g[o] = gmax[b*128+o]; __syncthreads();
  float acc = b0[o];
  for (int c = 0; c < 128; ++c) acc = fmaf(w0[o*256 + 128 + c], g[c], acc);
  gc[b*128+o] = acc;
}

// ---------------------------------------------------------------------------
// x = a + lf   (elementwise over [B,128,N]); a has per-batch stride abs_
// grid (256, B), block 256, float4
// ---------------------------------------------------------------------------
__global__ __launch_bounds__(256) void k_add(const float* __restrict__ a, long abs_,
                                             const float* __restrict__ lf,
                                             float* __restrict__ x)
{
  const int b = blockIdx.y;
  const long i = (long)blockIdx.x*256 + threadIdx.x;
  const float4* ap = (const float4*)(a  + (long)b*abs_);
  const float4* lp = (const float4*)(lf + (long)b*128*NPT);
  float4* xp = (float4*)(x + (long)b*128*NPT);
  float4 av = ap[i], lv = lp[i];
  xp[i] = make_float4(av.x+lv.x, av.y+lv.y, av.z+lv.z, av.w+lv.w);
}

// ---------------------------------------------------------------------------
// Row softmax stats: rmax[n] = max_m e[n,m], rsum[n] = sum_m exp(e-rmax),
// e[n,m] = sum_{k<32} q[k,n]*q[k,m].  grid (NPT/64, B), block 256.
// ---------------------------------------------------------------------------
__global__ __launch_bounds__(256) void k_rowstats(const float* __restrict__ q,
                                                  float* __restrict__ rmax,
                                                  float* __restrict__ rsum)
{
  const int b  = blockIdx.y;
  const int n0 = blockIdx.x * 64;
  const int tid = threadIdx.x;
  const int hi = tid & 15;
  const int lo = tid >> 4;
  __shared__ float qn[32][64];
  __shared__ float qm[32][128];
  __shared__ float mred[64*17];
  __shared__ float sred[64*17];
  const float* qbp = q + (long)b*32*NPT;
  for (int e = tid; e < 32*64; e += 256) { int k = e >> 6, n = e & 63; qn[k][n] = qbp[(long)k*NPT + n0 + n]; }
  float rm[4], rs[4];
  #pragma unroll
  for (int i=0;i<4;++i){ rm[i] = -FLT_MAX; rs[i] = 0.f; }

  for (int m0 = 0; m0 < NPT; m0 += 128) {
    __syncthreads();
    for (int e = tid; e < 32*128; e += 256) { int k = e >> 7, m = e & 127; qm[k][m] = qbp[(long)k*NPT + m0 + m]; }
    __syncthreads();
    float ee[4][8];
    #pragma unroll
    for (int i=0;i<4;++i)
      #pragma unroll
      for (int j=0;j<8;++j) ee[i][j] = 0.f;
    #pragma unroll
    for (int k=0;k<32;++k) {
      float a[4], xv[8];
      #pragma unroll
      for (int i=0;i<4;++i) a[i] = qn[k][lo*4+i];
      #pragma unroll
      for (int j=0;j<8;++j) xv[j] = qm[k][hi*8+j];
      #pragma unroll
      for (int i=0;i<4;++i)
        #pragma unroll
        for (int j=0;j<8;++j) ee[i][j] = fmaf(a[i], xv[j], ee[i][j]);
    }
    #pragma unroll
    for (int i=0;i<4;++i) {
      float mx = ee[i][0];
      #pragma unroll
      for (int j=1;j<8;++j) mx = fmaxf(mx, ee[i][j]);
      if (mx > rm[i]) { rs[i] *= __expf(rm[i]-mx); rm[i] = mx; }
      float s = 0.f;
      #pragma unroll
      for (int j=0;j<8;++j) s += __expf(ee[i][j]-rm[i]);
      rs[i] += s;
    }
  }
  #pragma unroll
  for (int i=0;i<4;++i) { mred[(lo*4+i)*17+hi] = rm[i]; sred[(lo*4+i)*17+hi] = rs[i]; }
  __syncthreads();
  if (tid < 64) {
    float gm = -FLT_MAX;
    for (int t=0;t<16;++t) gm = fmaxf(gm, mred[tid*17+t]);
    float gs = 0.f;
    for (int t=0;t<16;++t) gs += sred[tid*17+t]*__expf(mred[tid*17+t]-gm);
    rmax[(long)b*NPT + n0 + tid] = gm;
    rsum[(long)b*NPT + n0 + tid] = gs;
  }
}

// ---------------------------------------------------------------------------
// Attention pass 2: xr[b][c][m] = (sum_n v[c,n]*p[n,m]) / (1e-9 + sum_n p[n,m]),
// p[n,m] = exp(e[n,m]-rmax[n]) / rsum[n].  grid (NPT/128, B), block 256.
// ---------------------------------------------------------------------------
__global__ __launch_bounds__(256) void k_pass2(const float* __restrict__ q,
                                               const float* __restrict__ v,
                                               const float* __restrict__ rmax,
                                               const float* __restrict__ rsum,
                                               float* __restrict__ xr)
{
  const int b  = blockIdx.y;
  const int m0 = blockIdx.x * 128;
  const int tid = threadIdx.x;
  const int hi = tid & 15;
  const int lo = tid >> 4;
  __shared__ float qm[32][128];
  __shared__ float qn[32][32];
  __shared__ float vs[32][132];
  __shared__ float ps[32][128];
  __shared__ float csl[16*132];
  __shared__ float csf[128];
  const float* qbp = q + (long)b*32*NPT;
  const float* vbp = v + (long)b*128*NPT;
  for (int e = tid; e < 32*128; e += 256) { int k = e >> 7, m = e & 127; qm[k][m] = qbp[(long)k*NPT + m0 + m]; }
  float acc[8][8];
  #pragma unroll
  for (int i=0;i<8;++i)
    #pragma unroll
    for (int j=0;j<8;++j) acc[i][j] = 0.f;
  float cs[8];
  #pragma unroll
  for (int j=0;j<8;++j) cs[j] = 0.f;

  for (int n0 = 0; n0 < NPT; n0 += 32) {
    __syncthreads();
    for (int e = tid; e < 32*32; e += 256)  { int c = e >> 5, nn = e & 31; qn[c][nn] = qbp[(long)c*NPT + n0 + nn]; }
    for (int e = tid; e < 128*32; e += 256) { int c = e >> 5, nn = e & 31; vs[nn][c] = vbp[(long)c*NPT + n0 + nn]; }
    __syncthreads();
    float ee[2][8];
    #pragma unroll
    for (int i=0;i<2;++i)
      #pragma unroll
      for (int j=0;j<8;++j) ee[i][j] = 0.f;
    #pragma unroll
    for (int k=0;k<32;++k) {
      float a0 = qn[k][lo*2], a1 = qn[k][lo*2+1];
      float xv[8];
      #pragma unroll
      for (int j=0;j<8;++j) xv[j] = qm[k][hi*8+j];
      #pragma unroll
      for (int j=0;j<8;++j) {
        ee[0][j] = fmaf(a0, xv[j], ee[0][j]);
        ee[1][j] = fmaf(a1, xv[j], ee[1][j]);
      }
    }
    #pragma unroll
    for (int i=0;i<2;++i) {
      const int n = n0 + lo*2 + i;
      const float rmx = rmax[(long)b*NPT + n];
      const float irs = 1.f / rsum[(long)b*NPT + n];
      #pragma unroll
      for (int j=0;j<8;++j) {
        float p = __expf(ee[i][j] - rmx) * irs;
        ps[lo*2+i][hi*8+j] = p;
        cs[j] += p;
      }
    }
    __syncthreads();
    #pragma unroll 4
    for (int nn=0; nn<32; ++nn) {
      float vv[8], pp[8];
      #pragma unroll
      for (int i=0;i<8;++i) vv[i] = vs[nn][lo*8+i];
      #pragma unroll
      for (int j=0;j<8;++j) pp[j] = ps[nn][hi*8+j];
      #pragma unroll
      for (int i=0;i<8;++i)
        #pragma unroll
        for (int j=0;j<8;++j) acc[i][j] = fmaf(vv[i], pp[j], acc[i][j]);
    }
  }
  #pragma unroll
  for (int j=0;j<8;++j) csl[lo*132 + hi*8+j] = cs[j];
  __syncthreads();
  if (tid < 128) {
    float s = 0.f;
    for (int t=0;t<16;++t) s += csl[t*132 + tid];
    csf[tid] = 1.f/(1e-9f + s);
  }
  __syncthreads();
  float* xb = xr + (long)b*128*NPT;
  #pragma unroll
  for (int i=0;i<8;++i) {
    const int c = lo*8 + i;
    float* orow = xb + (long)c*NPT + m0 + hi*8;
    #pragma unroll
    for (int j=0;j<8;++j) orow[j] = acc[i][j] * csf[hi*8+j];
  }
}

// ---------------------------------------------------------------------------
// SA epilogue: out[b][ocol+o][n] = x[o][n] + relu( g'[o]*(wt@(x-xr)+bt)[o][n] + be[o] )
// ---------------------------------------------------------------------------
__global__ __launch_bounds__(256) void k_sa_final(
    const float* __restrict__ wt, const float* __restrict__ bt,
    const float* __restrict__ g,  const float* __restrict__ be,
    const float* __restrict__ x, const float* __restrict__ xr,
    float* __restrict__ out, long obs, int ocol)
{
  __shared__ float Ws[8][128];
  __shared__ float Xs[8][128];
  const int b  = blockIdx.y;
  const int n0 = blockIdx.x * 128;
  const int tid = threadIdx.x;
  const int tn = tid % 16;
  const int to = tid / 16;
  const float* xb  = x  + (long)b*128*NPT;
  const float* xrb = xr + (long)b*128*NPT;
  float acc[8][8];
  #pragma unroll
  for (int i=0;i<8;++i)
    #pragma unroll
    for (int j=0;j<8;++j) acc[i][j] = 0.f;

  for (int k0=0;k0<128;k0+=8) {
    for (int e = tid; e < 1024; e += 256) {
      int k = e % 8, o = e / 8;
      Ws[k][o] = wt[o*128 + k0 + k];
    }
    for (int e = tid; e < 1024; e += 256) {
      int k = e / 128, n = e % 128;
      long idx = (long)(k0+k)*NPT + n0 + n;
      Xs[k][n] = xb[idx] - xrb[idx];
    }
    __syncthreads();
    #pragma unroll
    for (int k=0;k<8;++k) {
      float a[8], xv[8];
      #pragma unroll
      for (int i=0;i<8;++i) a[i] = Ws[k][to*8+i];
      #pragma unroll
      for (int j=0;j<8;++j) xv[j] = Xs[k][tn*8+j];
      #pragma unroll
      for (int i=0;i<8;++i)
        #pragma unroll
        for (int j=0;j<8;++j) acc[i][j] = fmaf(a[i], xv[j], acc[i][j]);
    }
    __syncthreads();
  }
  const float bnsc = rsqrtf(1.f + 1e-5f);
  #pragma unroll
  for (int i=0;i<8;++i) {
    const int o = to*8 + i;
    const float bti = bt[o];
    const float gi  = g[o] * bnsc;
    const float bei = be[o];
    const float* xrow = xb + (long)o*NPT + n0 + tn*8;
    float* orow = out + (long)b*obs + (long)(ocol+o)*NPT + n0 + tn*8;
    #pragma unroll
    for (int j=0;j<8;++j) {
      float t  = acc[i][j] + bti;
      float val = fmaf(gi, t, bei);
      val = fmaxf(val, 0.f);
      orow[j] = xrow[j] + val;
    }
  }
}

// ---------------------------------------------------------------------------
// final: out[b*1024+o] = max over 16 tile-partials (fp32 output)
// ---------------------------------------------------------------------------
__global__ __launch_bounds__(256) void k_maxfinal(const float* __restrict__ part,
                                                  float* __restrict__ out)
{
  const int t = blockIdx.x*256 + threadIdx.x;   // 0..16383
  float m = -FLT_MAX;
  #pragma unroll
  for (int nt=0; nt<16; ++nt) m = fmaxf(m, part[(long)t*16+nt]);
  out[t] = m;
}

// ---------------------------------------------------------------------------
extern "C" void kernel_launch(void* const* d_in, const int* in_sizes, int n_in,
                              void* d_out, int out_size, void* d_ws, size_t ws_size,
                              hipStream_t stream)
{
  // Reference dtype is float32 -> ALL inputs and the output are fp32.
  const float* in   = (const float*)d_in[0];
  const float* m1w0 = (const float*)d_in[1];
  const float* m1b0 = (const float*)d_in[2];
  const float* m1w1 = (const float*)d_in[3];
  const float* m1b1 = (const float*)d_in[4];
  const float* m2w0 = (const float*)d_in[5];
  const float* m2b0 = (const float*)d_in[6];
  const float* m2w1 = (const float*)d_in[7];
  const float* m2b1 = (const float*)d_in[8];
  const float* m3w0 = (const float*)d_in[9];
  const float* m3b0 = (const float*)d_in[10];
  const float* m3w1 = (const float*)d_in[11];
  const float* m3b1 = (const float*)d_in[12];

  // ws layout (float offsets) — total 30,744,576 floats = 117.3 MiB, stats first.
  float* ws   = (float*)d_ws;
  float* rmax = ws;                      // [B,N]
  float* rsum = ws + 32768;              // [B,N]
  float* gmax = ws + 65536;              // [B,128]
  float* gc   = ws + 67584;              // [B,128]
  float* part = ws + 69632;              // [B,1024,16]
  float* lf   = ws + 335872;             // [B,128,N]
  float* xbuf = ws + 4530176;            // [B,128,N]
  float* qbuf = ws + 8724480;            // [B,32,N]
  float* vbuf = ws + 9773056;            // [B,128,N]
  float* xrbf = ws + 13967360;           // [B,128,N] (also mlp2 features)
  float* cat  = ws + 18161664;           // [B,384,N]
  float* hbuf = ws + 335872;             // [B,512,N] mlp3 hidden — aliases dead lf..xrbf

  const long S128 = (long)128*NPT;
  const dim3 blk(256);

  // mlp1
  k_mlp1a<<<dim3(NPT/256,128,NBAT), blk, 0, stream>>>(in, m1w0, m1b0, vbuf);
  conv_gemm<128,128,8,8,8,false,true,false,false><<<dim3(16,1,NBAT), blk, 0, stream>>>(
      m1w1,128,128, m1b1, nullptr,0, vbuf,S128, lf,S128,0, nullptr);
  // global max + mlp2
  k_gmax<<<dim3(NBAT*128), blk, 0, stream>>>(lf, gmax);
  k_gvec<<<dim3(NBAT), dim3(128), 0, stream>>>(m2w0, m2b0, gmax, gc);
  conv_gemm<128,128,8,8,8,true,false,true,false><<<dim3(16,1,NBAT), blk, 0, stream>>>(
      m2w0,256,128, nullptr, gc,128, lf,S128, vbuf,S128,0, nullptr);
  conv_gemm<128,128,8,8,8,false,true,false,false><<<dim3(16,1,NBAT), blk, 0, stream>>>(
      m2w1,128,128, m2b1, nullptr,0, vbuf,S128, xrbf,S128,0, nullptr);   // feat -> xrbf

  // 3 SA layers
  for (int L = 0; L < 3; ++L) {
    const float* wq = (const float*)d_in[13 + L*7 + 0];
    const float* wv = (const float*)d_in[13 + L*7 + 1];
    const float* bv = (const float*)d_in[13 + L*7 + 2];
    const float* wt = (const float*)d_in[13 + L*7 + 3];
    const float* bt = (const float*)d_in[13 + L*7 + 4];
    const float* gg = (const float*)d_in[13 + L*7 + 5];
    const float* be = (const float*)d_in[13 + L*7 + 6];

    const float* prev = (L == 0) ? xrbf : (cat + (long)(L-1)*128*NPT);
    const long prev_bs = (L == 0) ? S128 : (long)384*NPT;
    k_add<<<dim3(256,NBAT), blk, 0, stream>>>(prev, prev_bs, lf, xbuf);

    conv_gemm<32,128,8,2,8,false,false,false,false><<<dim3(16,1,NBAT), blk, 0, stream>>>(
        wq,128,128, nullptr, nullptr,0, xbuf,S128, qbuf,(long)32*NPT,0, nullptr);
    conv_gemm<128,128,8,8,8,false,true,false,false><<<dim3(16,1,NBAT), blk, 0, stream>>>(
        wv,128,128, bv, nullptr,0, xbuf,S128, vbuf,S128,0, nullptr);

    k_rowstats<<<dim3(NPT/64,NBAT), blk, 0, stream>>>(qbuf, rmax, rsum);
    k_pass2<<<dim3(NPT/128,NBAT), blk, 0, stream>>>(qbuf, vbuf, rmax, rsum, xrbf);
    k_sa_final<<<dim3(NPT/128,NBAT), blk, 0, stream>>>(
        wt, bt, gg, be, xbuf, xrbf, cat, (long)384*NPT, L*128);
  }

  // mlp3 (cat -> 512 relu -> 1024) fused max partials, then final max
  conv_gemm<128,128,8,8,8,true,true,false,false><<<dim3(16,4,NBAT), blk, 0, stream>>>(
      m3w0,384,384, m3b0, nullptr,0, cat,(long)384*NPT, hbuf,(long)512*NPT,0, nullptr);
  conv_gemm<128,128,8,8,8,false,true,false,true><<<dim3(16,8,NBAT), blk, 0, stream>>>(
      m3w1,512,512, m3b1, nullptr,1024, hbuf,(long)512*NPT, nullptr,0,0, part);
  k_maxfinal<<<dim3(64), blk, 0, stream>>>(part, (float*)d_out);
}

// Round 4
// 592.688 us; speedup vs baseline: 5.1724x; 5.1724x over previous
//
#include <hip/hip_runtime.h>
#include <hip/hip_bf16.h>
#include <cfloat>

static constexpr int NBAT = 16;
static constexpr int NPT  = 2048;

typedef _Float16 f16;
typedef _Float16 f16x8 __attribute__((ext_vector_type(8)));
typedef float    f32x4 __attribute__((ext_vector_type(4)));

static __device__ __forceinline__ f32x4 mfma16(f16x8 a, f16x8 b, f32x4 c){
  return __builtin_amdgcn_mfma_f32_16x16x32_f16(a, b, c, 0, 0, 0);
}
// MFMA 16x16x32 f16 layouts (gfx950):
//  A[16r x 32k]: lane l -> row l&15, k = (l>>4)*8 + j (16B contiguous)
//  B[32k x 16c]: lane l -> col l&15, k = (l>>4)*8 + j (16B contiguous)
//  D[16r x 16c]: lane l -> col l&15, rows (l>>4)*4 + i   [verified m89/m91]

// ---- weight arena offsets (halfs) ----
static constexpr long OFF_M1W1 = 0;              // [128][128]
static constexpr long OFF_M2W0A= 16384;          // [128][128] (cols 0..127 of [128][256])
static constexpr long OFF_M2W1 = 32768;          // [128][128]
static constexpr long OFF_M3W0 = 49152;          // [512][384]
static constexpr long OFF_M3W1 = 245760;         // [1024][512]
static constexpr long OFF_SA   = 770048;         // per-L: wq[32][128], wv[128][128], wt[128][128]
static constexpr long SA_STRIDE= 36864;
static constexpr long WTOT     = OFF_SA + 3*SA_STRIDE;   // 880,640 halfs

// ---------------------------------------------------------------------------
// weight fp32 -> fp16 conversion into arena (one launch)
// ---------------------------------------------------------------------------
__global__ __launch_bounds__(256) void k_wconv(
    const float* m1w1, const float* m2w0, const float* m2w1,
    const float* m3w0, const float* m3w1,
    const float* wq0, const float* wv0, const float* wt0,
    const float* wq1, const float* wv1, const float* wt1,
    const float* wq2, const float* wv2, const float* wt2,
    f16* W)
{
  long t = (long)blockIdx.x*256 + threadIdx.x;
  if (t >= WTOT) return;
  float v;
  if      (t < OFF_M2W0A) v = m1w1[t];
  else if (t < OFF_M2W1) { long u = t-OFF_M2W0A; v = m2w0[(u>>7)*256 + (u&127)]; }
  else if (t < OFF_M3W0)  v = m2w1[t-OFF_M2W1];
  else if (t < OFF_M3W1)  v = m3w0[t-OFF_M3W0];
  else if (t < OFF_SA)    v = m3w1[t-OFF_M3W1];
  else {
    long u = t - OFF_SA; int L = (int)(u / SA_STRIDE); long r = u % SA_STRIDE;
    const float* wq = (L==0)?wq0:(L==1)?wq1:wq2;
    const float* wv = (L==0)?wv0:(L==1)?wv1:wv2;
    const float* wt = (L==0)?wt0:(L==1)?wt1:wt2;
    if (r < 4096) v = wq[r]; else if (r < 20480) v = wv[r-4096]; else v = wt[r-20480];
  }
  W[t] = (f16)v;
}

// ---------------------------------------------------------------------------
// mlp1 layer0 (K=3): h1T[b][n][o] = relu(b0[o] + sum_c w0[o][c]*in[b][n][c])
// grid 16*2048*32/256, each thread 4 outputs
// ---------------------------------------------------------------------------
__global__ __launch_bounds__(256) void k_mlp1aT(const float* __restrict__ in,
                                                const float* __restrict__ w0,
                                                const float* __restrict__ b0,
                                                f16* __restrict__ h1T)
{
  long idx = (long)blockIdx.x*256 + threadIdx.x;
  int og = idx & 31; long bn = idx >> 5;
  const float* ip = in + bn*3;
  float x0=ip[0], x1=ip[1], x2=ip[2];
  f16* op = h1T + bn*128 + og*4;
  #pragma unroll
  for (int i=0;i<4;++i){
    int o = og*4+i;
    float v = b0[o] + w0[o*3]*x0 + w0[o*3+1]*x1 + w0[o*3+2]*x2;
    op[i] = (f16)fmaxf(v, 0.f);
  }
}

// ---------------------------------------------------------------------------
// generic transposed conv GEMM: OUTT[b][n][ocol+o] = act(bias + sum_k XT[b][n][k]*W[o][k])
// OT in {32,64}. block 256 (4 waves), tile 64n x OTo, BK=64.
// ---------------------------------------------------------------------------
template<int OT, bool RELU, bool B2D>
__global__ __launch_bounds__(256) void gemmT(
    const f16* __restrict__ W, const float* __restrict__ bias,
    const float* __restrict__ bias2d,
    const f16* __restrict__ XT, int xrs,
    f16* __restrict__ OUT, int ors, int ocol, int K)
{
  __shared__ __align__(16) f16 Xs[64][72];
  __shared__ __align__(16) f16 Wsh[OT][72];
  const int b  = blockIdx.z;
  const int n0 = blockIdx.x * 64;
  const int o0 = blockIdx.y * OT;
  const int tid = threadIdx.x, lane = tid & 63, w = tid >> 6;
  const int lr = lane & 15, lg = lane >> 4;
  constexpr int NSUB = (OT==64)?2:1;
  const int wn = (OT==64)? (w>>1) : w;
  const int wo = (OT==64)? (w&1) : 0;
  const int nbase = wn*(16*NSUB);
  const f16* Xb = XT + (long)b*NPT*xrs;
  f32x4 acc[NSUB][2];
  #pragma unroll
  for (int ni=0;ni<NSUB;++ni){ acc[ni][0]=(f32x4){0,0,0,0}; acc[ni][1]=(f32x4){0,0,0,0}; }

  for (int k0=0; k0<K; k0+=64){
    #pragma unroll
    for (int g = tid; g < 512; g += 256){
      int r = g>>3, s = g&7;
      *(float4*)&Xs[r][s*8] = *(const float4*)(Xb + (long)(n0+r)*xrs + k0 + s*8);
    }
    for (int g = tid; g < OT*8; g += 256){
      int r = g>>3, s = g&7;
      *(float4*)&Wsh[r][s*8] = *(const float4*)(W + (long)(o0+r)*K + k0 + s*8);
    }
    __syncthreads();
    #pragma unroll
    for (int ks=0; ks<2; ++ks){
      f16x8 a[NSUB], bf[2];
      #pragma unroll
      for (int ni=0;ni<NSUB;++ni) a[ni] = *(const f16x8*)&Xs[nbase + ni*16 + lr][ks*32 + lg*8];
      #pragma unroll
      for (int oi=0;oi<2;++oi)   bf[oi] = *(const f16x8*)&Wsh[wo*32 + oi*16 + lr][ks*32 + lg*8];
      #pragma unroll
      for (int ni=0;ni<NSUB;++ni)
        #pragma unroll
        for (int oi=0;oi<2;++oi) acc[ni][oi] = mfma16(a[ni], bf[oi], acc[ni][oi]);
    }
    __syncthreads();
  }
  #pragma unroll
  for (int ni=0;ni<NSUB;++ni)
    #pragma unroll
    for (int oi=0;oi<2;++oi){
      const int oc = o0 + wo*32 + oi*16 + lr;
      float bi = bias ? bias[oc] : 0.f;
      if constexpr (B2D) bi += bias2d[b*128 + oc];
      #pragma unroll
      for (int i=0;i<4;++i){
        const int nn = n0 + nbase + ni*16 + lg*4 + i;
        float v = acc[ni][oi][i] + bi;
        if constexpr (RELU) v = fmaxf(v, 0.f);
        OUT[(long)b*NPT*ors + (long)nn*ors + ocol + oc] = (f16)v;
      }
    }
}

// ---------------------------------------------------------------------------
// v GEMM: v16[b][c][n] = bv[c] + sum_k Wv[c][k]*XT[b][n][k]  (c rows, n cols)
// tile 64c x 64n, grid (32, 2, B)
// ---------------------------------------------------------------------------
__global__ __launch_bounds__(256) void vgemm(
    const f16* __restrict__ Wv, const float* __restrict__ bv,
    const f16* __restrict__ XT, f16* __restrict__ v16)
{
  __shared__ __align__(16) f16 Xs[64][72];
  __shared__ __align__(16) f16 Wsh[64][72];
  const int b  = blockIdx.z;
  const int n0 = blockIdx.x * 64;
  const int c0 = blockIdx.y * 64;
  const int tid = threadIdx.x, lane = tid & 63, w = tid >> 6;
  const int lr = lane & 15, lg = lane >> 4;
  const int wc = w>>1, wn = w&1;
  const f16* Xb = XT + (long)b*NPT*128;
  f32x4 acc[2][2];
  #pragma unroll
  for (int ci=0;ci<2;++ci){ acc[ci][0]=(f32x4){0,0,0,0}; acc[ci][1]=(f32x4){0,0,0,0}; }

  for (int k0=0; k0<128; k0+=64){
    #pragma unroll
    for (int g = tid; g < 512; g += 256){
      int r = g>>3, s = g&7;
      *(float4*)&Xs[r][s*8]  = *(const float4*)(Xb + (long)(n0+r)*128 + k0 + s*8);
      *(float4*)&Wsh[r][s*8] = *(const float4*)(Wv + (long)(c0+r)*128 + k0 + s*8);
    }
    __syncthreads();
    #pragma unroll
    for (int ks=0; ks<2; ++ks){
      f16x8 a[2], bf[2];
      #pragma unroll
      for (int ci=0;ci<2;++ci) a[ci] = *(const f16x8*)&Wsh[wc*32 + ci*16 + lr][ks*32 + lg*8];
      #pragma unroll
      for (int ni=0;ni<2;++ni) bf[ni] = *(const f16x8*)&Xs[wn*32 + ni*16 + lr][ks*32 + lg*8];
      #pragma unroll
      for (int ci=0;ci<2;++ci)
        #pragma unroll
        for (int ni=0;ni<2;++ni) acc[ci][ni] = mfma16(a[ci], bf[ni], acc[ci][ni]);
    }
    __syncthreads();
  }
  #pragma unroll
  for (int ci=0;ci<2;++ci)
    #pragma unroll
    for (int i=0;i<4;++i){
      const int c = c0 + wc*32 + ci*16 + lg*4 + i;
      const float bi = bv[c];
      #pragma unroll
      for (int ni=0;ni<2;++ni){
        const int n = n0 + wn*32 + ni*16 + lr;
        v16[(long)b*128*NPT + (long)c*NPT + n] = (f16)(acc[ci][ni][i] + bi);
      }
    }
}

// ---------------------------------------------------------------------------
// rowstats via MFMA: rmax/rsum over m of e[m,n] (symmetric e) per col n.
// block: n-tile 64 (wave w -> 16 cols), sweep m. grid (32, B)
// ---------------------------------------------------------------------------
__global__ __launch_bounds__(256) void k_rowstats2(const f16* __restrict__ qT,
                                                   float* __restrict__ rmax,
                                                   float* __restrict__ rsum)
{
  const int b = blockIdx.y, n0 = blockIdx.x*64;
  const int tid = threadIdx.x, lane = tid & 63, w = tid >> 6;
  const int lr = lane & 15, lg = lane >> 4;
  const f16* qb = qT + (long)b*NPT*32;
  const f16x8 bfr = *(const f16x8*)(qb + (long)(n0 + w*16 + lr)*32 + lg*8);
  float mx = -1e30f, sm = 0.f;
  for (int m0=0; m0<NPT; m0+=16){
    f16x8 af = *(const f16x8*)(qb + (long)(m0+lr)*32 + lg*8);
    f32x4 e = mfma16(af, bfr, (f32x4){0,0,0,0});
    float tmx = fmaxf(fmaxf(e[0],e[1]), fmaxf(e[2],e[3]));
    if (tmx > mx){ sm *= __expf(mx - tmx); mx = tmx; }
    sm += __expf(e[0]-mx) + __expf(e[1]-mx) + __expf(e[2]-mx) + __expf(e[3]-mx);
  }
  #pragma unroll
  for (int d=16; d<64; d<<=1){
    float omx = __shfl_xor(mx, d, 64);
    float osm = __shfl_xor(sm, d, 64);
    float nm = fmaxf(mx, omx);
    sm = sm*__expf(mx-nm) + osm*__expf(omx-nm);
    mx = nm;
  }
  if (lane < 16){
    rmax[(long)b*NPT + n0 + w*16 + lr] = mx;
    rsum[(long)b*NPT + n0 + w*16 + lr] = sm;
  }
}

// ---------------------------------------------------------------------------
// pass2 via MFMA: xrT[b][m][c] = (sum_n p[n,m] v[c,n]) / (1e-9 + sum_n p[n,m])
// block: m-tile 64 (wave w -> 16 m rows), loop n-tiles of 32. grid (32, B)
// ---------------------------------------------------------------------------
__global__ __launch_bounds__(256) void k_pass2m(const f16* __restrict__ qT,
                                                const f16* __restrict__ v16,
                                                const float* __restrict__ rmax,
                                                const float* __restrict__ rsum,
                                                f16* __restrict__ xrT)
{
  __shared__ __align__(16) f16 ps[64][40];   // pT[m][n-tile]
  __shared__ __align__(16) f16 vs[128][40];  // v-tile [c][n-tile]
  __shared__ float csf[64];
  const int b = blockIdx.y, m0 = blockIdx.x*64;
  const int tid = threadIdx.x, lane = tid & 63, w = tid >> 6;
  const int lr = lane & 15, lg = lane >> 4;
  const f16* qb = qT + (long)b*NPT*32;
  const f16* vb = v16 + (long)b*128*NPT;
  const float* rmx = rmax + (long)b*NPT;
  const float* rsm = rsum + (long)b*NPT;
  const f16x8 afe = *(const f16x8*)(qb + (long)(m0 + w*16 + lr)*32 + lg*8);  // E A-frag (rows m)
  f32x4 acc[8];
  #pragma unroll
  for (int cg=0; cg<8; ++cg) acc[cg] = (f32x4){0,0,0,0};
  float cs = 0.f;

  for (int nt=0; nt<NPT; nt+=32){
    // stage v-tile [128c][32n] into padded LDS
    #pragma unroll
    for (int g = tid; g < 512; g += 256){
      int c = g>>2, s = g&3;
      *(float4*)&vs[c][s*8] = *(const float4*)(vb + (long)c*NPT + nt + s*8);
    }
    // E phase: 2 col-groups; lane col n fixed, 4 m-rows
    #pragma unroll
    for (int ng=0; ng<2; ++ng){
      f16x8 bfe = *(const f16x8*)(qb + (long)(nt + ng*16 + lr)*32 + lg*8);
      f32x4 e = mfma16(afe, bfe, (f32x4){0,0,0,0});
      const int n = nt + ng*16 + lr;
      const float rm = rmx[n];
      const float irs = 1.f / rsm[n];
      #pragma unroll
      for (int i=0;i<4;++i){
        float p = __expf(e[i] - rm) * irs;
        ps[w*16 + lg*4 + i][ng*16 + lr] = (f16)p;
      }
    }
    __syncthreads();
    // PV phase: A = pT rows m (wave-private), B = v-tile cols c
    f16x8 ap = *(const f16x8*)&ps[w*16 + lr][lg*8];
    #pragma unroll
    for (int j=0;j<8;++j) cs += (float)ap[j];
    #pragma unroll
    for (int cg=0; cg<8; ++cg){
      f16x8 bp = *(const f16x8*)&vs[cg*16 + lr][lg*8];
      acc[cg] = mfma16(ap, bp, acc[cg]);
    }
    __syncthreads();
  }
  // colsum across the 4 n-slice groups (same m row)
  cs += __shfl_xor(cs, 16, 64);
  cs += __shfl_xor(cs, 32, 64);
  if (lg == 0) csf[w*16 + lr] = 1.f/(1e-9f + cs);
  __syncthreads();
  float ci[4];
  #pragma unroll
  for (int i=0;i<4;++i) ci[i] = csf[w*16 + lg*4 + i];
  f16* xb = xrT + (long)b*NPT*128;
  #pragma unroll
  for (int cg=0; cg<8; ++cg)
    #pragma unroll
    for (int i=0;i<4;++i)
      xb[(long)(m0 + w*16 + lg*4 + i)*128 + cg*16 + lr] = (f16)(acc[cg][i] * ci[i]);
}

// ---------------------------------------------------------------------------
// xT = prev + lfT (fp16 vector add). grid 16*2048*16/256
// ---------------------------------------------------------------------------
__global__ __launch_bounds__(256) void k_addT(const f16* __restrict__ prev, int prs, int pcol,
                                              const f16* __restrict__ lfT,
                                              f16* __restrict__ xT)
{
  long idx = (long)blockIdx.x*256 + threadIdx.x;
  long bn = idx >> 4; int c8 = (int)(idx & 15);
  f16x8 a = *(const f16x8*)(prev + bn*prs + pcol + c8*8);
  f16x8 l = *(const f16x8*)(lfT + bn*128 + c8*8);
  *(f16x8*)(xT + bn*128 + c8*8) = a + l;
}

// ---------------------------------------------------------------------------
// gmax over n per (b,c): block 1024 per batch (8 n-strips x 128 c)
// ---------------------------------------------------------------------------
__global__ __launch_bounds__(1024) void k_gmaxT(const f16* __restrict__ lfT,
                                                float* __restrict__ gmaxv)
{
  __shared__ float red[8][128];
  const int b = blockIdx.x;
  const int c = threadIdx.x & 127, h = threadIdx.x >> 7;
  const f16* p = lfT + (long)b*NPT*128;
  float m = -1e30f;
  for (int n = h*256; n < (h+1)*256; ++n) m = fmaxf(m, (float)p[(long)n*128 + c]);
  red[h][c] = m; __syncthreads();
  if (threadIdx.x < 128){
    float mm = red[0][c];
    #pragma unroll
    for (int j=1;j<8;++j) mm = fmaxf(mm, red[j][c]);
    gmaxv[b*128 + c] = mm;
  }
}

// gc[b][o] = b0[o] + sum_c w0[o][128+c]*gmax[b][c]  (fp32 weights)
__global__ __launch_bounds__(128) void k_gvec(const float* __restrict__ w0,
                                              const float* __restrict__ b0,
                                              const float* __restrict__ gmaxv,
                                              float* __restrict__ gc)
{
  const int b = blockIdx.x, o = threadIdx.x;
  __shared__ float g[128];
  g[o] = gmaxv[b*128+o]; __syncthreads();
  float acc = b0[o];
  for (int c = 0; c < 128; ++c) acc = fmaf(w0[o*256 + 128 + c], g[c], acc);
  gc[b*128+o] = acc;
}

// ---------------------------------------------------------------------------
// SA epilogue GEMM: cat[b][n][Lcol+o] = x[n][o] + relu(g'[o]*(wt@(x-xr))[n][o]+bt'..)
// structure = gemmT(OT=64,K=128) with diff staging + fused epilogue
// ---------------------------------------------------------------------------
__global__ __launch_bounds__(256) void k_safin(
    const f16* __restrict__ Wt, const float* __restrict__ bt,
    const float* __restrict__ g, const float* __restrict__ be,
    const f16* __restrict__ xT, const f16* __restrict__ xrT,
    f16* __restrict__ cat, int Lcol)
{
  __shared__ __align__(16) f16 Xs[64][72];
  __shared__ __align__(16) f16 Wsh[64][72];
  const int b  = blockIdx.z;
  const int n0 = blockIdx.x * 64;
  const int o0 = blockIdx.y * 64;
  const int tid = threadIdx.x, lane = tid & 63, w = tid >> 6;
  const int lr = lane & 15, lg = lane >> 4;
  const int wn = w>>1, wo = w&1;
  const f16* xb  = xT  + (long)b*NPT*128;
  const f16* xrb = xrT + (long)b*NPT*128;
  f32x4 acc[2][2];
  #pragma unroll
  for (int ni=0;ni<2;++ni){ acc[ni][0]=(f32x4){0,0,0,0}; acc[ni][1]=(f32x4){0,0,0,0}; }

  for (int k0=0; k0<128; k0+=64){
    #pragma unroll
    for (int gidx = tid; gidx < 512; gidx += 256){
      int r = gidx>>3, s = gidx&7;
      f16x8 xa = *(const f16x8*)(xb  + (long)(n0+r)*128 + k0 + s*8);
      f16x8 xr = *(const f16x8*)(xrb + (long)(n0+r)*128 + k0 + s*8);
      *(f16x8*)&Xs[r][s*8] = xa - xr;
      *(float4*)&Wsh[r][s*8] = *(const float4*)(Wt + (long)(o0+r)*128 + k0 + s*8);
    }
    __syncthreads();
    #pragma unroll
    for (int ks=0; ks<2; ++ks){
      f16x8 a[2], bf[2];
      #pragma unroll
      for (int ni=0;ni<2;++ni) a[ni] = *(const f16x8*)&Xs[wn*32 + ni*16 + lr][ks*32 + lg*8];
      #pragma unroll
      for (int oi=0;oi<2;++oi) bf[oi] = *(const f16x8*)&Wsh[wo*32 + oi*16 + lr][ks*32 + lg*8];
      #pragma unroll
      for (int ni=0;ni<2;++ni)
        #pragma unroll
        for (int oi=0;oi<2;++oi) acc[ni][oi] = mfma16(a[ni], bf[oi], acc[ni][oi]);
    }
    __syncthreads();
  }
  const float bnsc = rsqrtf(1.f + 1e-5f);
  #pragma unroll
  for (int ni=0;ni<2;++ni)
    #pragma unroll
    for (int oi=0;oi<2;++oi){
      const int oc = o0 + wo*32 + oi*16 + lr;
      const float bti = bt[oc], gi = g[oc]*bnsc, bei = be[oc];
      #pragma unroll
      for (int i=0;i<4;++i){
        const int nn = n0 + wn*32 + ni*16 + lg*4 + i;
        float t = acc[ni][oi][i] + bti;
        float val = fmaxf(fmaf(gi, t, bei), 0.f);
        float res = (float)xb[(long)nn*128 + oc];
        cat[(long)b*NPT*384 + (long)nn*384 + Lcol + oc] = (f16)(res + val);
      }
    }
}

// ---------------------------------------------------------------------------
// mlp3 layer1 with fused max: part[(b*1024+o)*32 + bx] = max_n(W.h + b)
// tile 64n x 64o, K=512. grid (32, 16, B)
// ---------------------------------------------------------------------------
__global__ __launch_bounds__(256) void k_gemmax(
    const f16* __restrict__ W, const float* __restrict__ bias,
    const f16* __restrict__ XT, float* __restrict__ part)
{
  __shared__ __align__(16) f16 Xs[64][72];
  __shared__ __align__(16) f16 Wsh[64][72];
  __shared__ float red[2][64];
  const int b  = blockIdx.z;
  const int n0 = blockIdx.x * 64;
  const int o0 = blockIdx.y * 64;
  const int tid = threadIdx.x, lane = tid & 63, w = tid >> 6;
  const int lr = lane & 15, lg = lane >> 4;
  const int wn = w>>1, wo = w&1;
  const f16* Xb = XT + (long)b*NPT*512;
  f32x4 acc[2][2];
  #pragma unroll
  for (int ni=0;ni<2;++ni){ acc[ni][0]=(f32x4){0,0,0,0}; acc[ni][1]=(f32x4){0,0,0,0}; }

  for (int k0=0; k0<512; k0+=64){
    #pragma unroll
    for (int g = tid; g < 512; g += 256){
      int r = g>>3, s = g&7;
      *(float4*)&Xs[r][s*8]  = *(const float4*)(Xb + (long)(n0+r)*512 + k0 + s*8);
      *(float4*)&Wsh[r][s*8] = *(const float4*)(W + (long)(o0+r)*512 + k0 + s*8);
    }
    __syncthreads();
    #pragma unroll
    for (int ks=0; ks<2; ++ks){
      f16x8 a[2], bf[2];
      #pragma unroll
      for (int ni=0;ni<2;++ni) a[ni] = *(const f16x8*)&Xs[wn*32 + ni*16 + lr][ks*32 + lg*8];
      #pragma unroll
      for (int oi=0;oi<2;++oi) bf[oi] = *(const f16x8*)&Wsh[wo*32 + oi*16 + lr][ks*32 + lg*8];
      #pragma unroll
      for (int ni=0;ni<2;++ni)
        #pragma unroll
        for (int oi=0;oi<2;++oi) acc[ni][oi] = mfma16(a[ni], bf[oi], acc[ni][oi]);
    }
    __syncthreads();
  }
  #pragma unroll
  for (int oi=0;oi<2;++oi){
    const int oc = o0 + wo*32 + oi*16 + lr;
    float bi = bias[oc];
    float mv = -1e30f;
    #pragma unroll
    for (int ni=0;ni<2;++ni)
      #pragma unroll
      for (int i=0;i<4;++i) mv = fmaxf(mv, acc[ni][oi][i] + bi);
    mv = fmaxf(mv, __shfl_xor(mv, 16, 64));
    mv = fmaxf(mv, __shfl_xor(mv, 32, 64));
    if (lg == 0) red[wn][wo*32 + oi*16 + lr] = mv;
  }
  __syncthreads();
  if (tid < 64)
    part[((long)b*1024 + o0 + tid)*32 + blockIdx.x] = fmaxf(red[0][tid], red[1][tid]);
}

__global__ __launch_bounds__(256) void k_maxfinal(const float* __restrict__ part,
                                                  float* __restrict__ out)
{
  const int t = blockIdx.x*256 + threadIdx.x;   // 0..16383
  float m = -1e30f;
  #pragma unroll
  for (int j=0;j<32;++j) m = fmaxf(m, part[(long)t*32 + j]);
  out[t] = m;
}

// ---------------------------------------------------------------------------
extern "C" void kernel_launch(void* const* d_in, const int* in_sizes, int n_in,
                              void* d_out, int out_size, void* d_ws, size_t ws_size,
                              hipStream_t stream)
{
  const float* in   = (const float*)d_in[0];
  const float* m1w0 = (const float*)d_in[1];
  const float* m1b0 = (const float*)d_in[2];
  const float* m1w1 = (const float*)d_in[3];
  const float* m1b1 = (const float*)d_in[4];
  const float* m2w0 = (const float*)d_in[5];
  const float* m2b0 = (const float*)d_in[6];
  const float* m2w1 = (const float*)d_in[7];
  const float* m2b1 = (const float*)d_in[8];
  const float* m3w0 = (const float*)d_in[9];
  const float* m3b0 = (const float*)d_in[10];
  const float* m3w1 = (const float*)d_in[11];
  const float* m3b1 = (const float*)d_in[12];

  // ws layout (halfs; ~98.5 MB total, fits proven 117 MiB)
  f16* ws16 = (f16*)d_ws;
  f16* W16  = ws16;                       // 880,640
  f16* lfT  = ws16 + 880640;              // [B][N][128]
  f16* xT   = ws16 + 5074944;             // [B][N][128]
  f16* qT   = ws16 + 9269248;             // [B][N][32]
  f16* v16  = ws16 + 10317824;            // [B][128][N]
  f16* xrT  = ws16 + 14512128;            // [B][N][128] (also mlp2 features)
  f16* hT   = ws16 + 18706432;            // [B][N][512] (also h1T / mlp2-hidden)
  f16* catT = ws16 + 35483648;            // [B][N][384]
  float* fb = (float*)(ws16 + 48066560);
  float* rmaxp = fb;                      // [B,N]
  float* rsump = fb + 32768;
  float* gmaxv = fb + 65536;              // [B,128]
  float* gc    = fb + 67584;              // [B,128]
  float* part  = fb + 69632;              // [B,1024,32]

  const dim3 blk(256);

  k_wconv<<<dim3((WTOT+255)/256), blk, 0, stream>>>(
      m1w1, m2w0, m2w1, m3w0, m3w1,
      (const float*)d_in[13], (const float*)d_in[14], (const float*)d_in[16],
      (const float*)d_in[20], (const float*)d_in[21], (const float*)d_in[23],
      (const float*)d_in[27], (const float*)d_in[28], (const float*)d_in[30],
      W16);

  // mlp1
  k_mlp1aT<<<dim3(NBAT*NPT*32/256), blk, 0, stream>>>(in, m1w0, m1b0, hT);
  gemmT<64,false,false><<<dim3(32,2,NBAT), blk, 0, stream>>>(
      W16+OFF_M1W1, m1b1, nullptr, hT, 128, lfT, 128, 0, 128);
  // global max + mlp2
  k_gmaxT<<<dim3(NBAT), dim3(1024), 0, stream>>>(lfT, gmaxv);
  k_gvec<<<dim3(NBAT), dim3(128), 0, stream>>>(m2w0, m2b0, gmaxv, gc);
  gemmT<64,true,true><<<dim3(32,2,NBAT), blk, 0, stream>>>(
      W16+OFF_M2W0A, nullptr, gc, lfT, 128, hT, 128, 0, 128);
  gemmT<64,false,false><<<dim3(32,2,NBAT), blk, 0, stream>>>(
      W16+OFF_M2W1, m2b1, nullptr, hT, 128, xrT, 128, 0, 128);   // features -> xrT

  // 3 SA layers
  for (int L = 0; L < 3; ++L){
    const float* bv = (const float*)d_in[13 + L*7 + 2];
    const float* bt = (const float*)d_in[13 + L*7 + 4];
    const float* gg = (const float*)d_in[13 + L*7 + 5];
    const float* be = (const float*)d_in[13 + L*7 + 6];
    const f16* wq16 = W16 + OFF_SA + L*SA_STRIDE;
    const f16* wv16 = wq16 + 4096;
    const f16* wt16 = wq16 + 20480;

    const f16* prev = (L==0) ? xrT : (catT + (long)(L-1)*128);
    const int  prs  = (L==0) ? 128 : 384;
    k_addT<<<dim3(NBAT*NPT*16/256), blk, 0, stream>>>(prev, prs, 0, lfT, xT);

    gemmT<32,false,false><<<dim3(32,1,NBAT), blk, 0, stream>>>(
        wq16, nullptr, nullptr, xT, 128, qT, 32, 0, 128);
    vgemm<<<dim3(32,2,NBAT), blk, 0, stream>>>(wv16, bv, xT, v16);
    k_rowstats2<<<dim3(32,NBAT), blk, 0, stream>>>(qT, rmaxp, rsump);
    k_pass2m<<<dim3(32,NBAT), blk, 0, stream>>>(qT, v16, rmaxp, rsump, xrT);
    k_safin<<<dim3(32,2,NBAT), blk, 0, stream>>>(wt16, bt, gg, be, xT, xrT, catT, L*128);
  }

  // mlp3
  gemmT<64,true,false><<<dim3(32,8,NBAT), blk, 0, stream>>>(
      W16+OFF_M3W0, m3b0, nullptr, catT, 384, hT, 512, 0, 384);
  k_gemmax<<<dim3(32,16,NBAT), blk, 0, stream>>>(W16+OFF_M3W1, m3b1, hT, part);
  k_maxfinal<<<dim3(64), blk, 0, stream>>>(part, (float*)d_out);
}